// Round 14
// baseline (1009.464 us; speedup 1.0000x reference)
//
#include <hip/hip_runtime.h>
#include <cstdint>
#include <cstddef>

// BinSAGE: 2-layer GraphSAGE with sign-binarized weights. MFMA bf16 + bucketed edges.
// N=50000 nodes, E=800000 edges, dims 96 -> 128 -> 64.
//   count_prep: 64 blocks histogram dst>>8; other blocks S1t/S2t + xb=bf16(x).
//   bucket_scan (1 block) -> bucketBase/cursors.
//   bucket_scatter -> bucketBuf packed (src | localDst<<16), dense runs.
//   agg1_bucket: block=bucket, EDGE-PARALLEL gather of xb rows, accumulate into
//     LDS f32 [256][97] via ds_add (bank-uniform: bank(ld*97+f)=(ld+f)%32),
//     deg histogram in-loop, epilogue writes AGGb bf16.
//   gemm12 (fused MFMA, B staged in LDS): [AGGb|xb] @ S1t^T -> relu -> H (LDS)
//                                         H @ S2t^T -> T2b bf16 + R2 f32
//   final_bucket: same edge-parallel pattern over T2b, LDS f32 [256][65].
// R13 bug fixed: agg1 gather loads strided q*16 u16 (32B) but accumulate
// assumed q*8 -> half the features skipped (absmax 133). Now q*8 throughout.
// R12 lesson: subgroup gathers capped by per-wave concurrency; edge-parallel
// gives each thread an independent row (hundreds of lines in flight/block).
// R9 lesson: GEMM B LDS-staged. R7 lesson: AGGb disjoint from T2b/R2.

#define N_NODES 50000
#define IN_DIM 96
#define HID 128
#define OUT_DIM 64
#define CNT_BLOCKS 64

typedef __attribute__((ext_vector_type(8))) short bf16x8;
typedef __attribute__((ext_vector_type(4))) float f32x4;

static inline size_t alignUp(size_t v, size_t a) { return (v + a - 1) & ~(a - 1); }

__device__ __forceinline__ uint16_t f2bf(float f) {
  uint32_t u = __float_as_uint(f);
  return (uint16_t)((u + 0x7FFF + ((u >> 16) & 1)) >> 16);
}
__device__ __forceinline__ float bflo(uint32_t v) { return __uint_as_float(v << 16); }
__device__ __forceinline__ float bfhi(uint32_t v) { return __uint_as_float(v & 0xFFFF0000u); }
__device__ __forceinline__ uint16_t sgnbf(float w) {
  return (w > 0.f) ? (uint16_t)0x3F80 : ((w < 0.f) ? (uint16_t)0xBF80 : (uint16_t)0);
}

#define NS1 (128 * 192)
#define NS2 (128 * 128)

// ---------------- merged: bucket count (64 partial rows) + prep ----------------
__global__ __launch_bounds__(256) void count_prep_kernel(const int* __restrict__ dst,
    int* __restrict__ bucketPart, int E,
    const float* __restrict__ x,
    const float* __restrict__ w1l, const float* __restrict__ w1r,
    const float* __restrict__ w2l, const float* __restrict__ w2r,
    uint16_t* __restrict__ S1t, uint16_t* __restrict__ S2t,
    uint16_t* __restrict__ xb, int total4) {
  __shared__ int h[256];
  const int t = threadIdx.x;
  if (blockIdx.x < CNT_BLOCKS) {
    h[t] = 0;
    __syncthreads();
    const int stride = CNT_BLOCKS * 256;
    for (int i = blockIdx.x * 256 + t; i < E; i += stride)
      atomicAdd(&h[dst[i] >> 8], 1);
    __syncthreads();
    bucketPart[blockIdx.x * 256 + t] = h[t];
  } else {
    const int idx = (blockIdx.x - CNT_BLOCKS) * 256 + t;
    if (idx < NS1) {
      int n = idx / 192, k = idx - n * 192;
      float w = (k < 96) ? w1l[n * 96 + k] : w1r[n * 96 + (k - 96)];
      S1t[idx] = sgnbf(w);
    } else if (idx < NS1 + NS2) {
      int i2 = idx - NS1;
      int n = i2 >> 7, k = i2 & 127;
      float w = (n < 64) ? w2l[n * 128 + k] : w2r[(n - 64) * 128 + k];
      S2t[i2] = sgnbf(w);
    } else {
      int i = idx - NS1 - NS2;
      if (i < total4) {
        float4 v = *(const float4*)(x + (size_t)i * 4);
        uint32_t p0 = (uint32_t)f2bf(v.x) | ((uint32_t)f2bf(v.y) << 16);
        uint32_t p1 = (uint32_t)f2bf(v.z) | ((uint32_t)f2bf(v.w) << 16);
        *(uint2*)(xb + (size_t)i * 4) = make_uint2(p0, p1);
      }
    }
  }
}

// 1 block: column-sum 64 partial rows -> scan -> bases/cursors.
__global__ __launch_bounds__(256) void bucket_scan_kernel(const int* __restrict__ bucketPart,
    int* __restrict__ bucketBase, int* __restrict__ bucketCursor, int nB) {
  __shared__ int smem[256];
  const int t = threadIdx.x;
  int v = 0;
  for (int b = 0; b < CNT_BLOCKS; ++b) v += bucketPart[b * 256 + t];
  if (t >= nB) v = 0;
  smem[t] = v;
  __syncthreads();
  for (int off = 1; off < 256; off <<= 1) {
    int u = (t >= off) ? smem[t - off] : 0;
    __syncthreads();
    smem[t] += u;
    __syncthreads();
  }
  if (t < nB) {
    const int excl = smem[t] - v;
    bucketBase[t] = excl;
    bucketCursor[t] = excl;
  }
  if (t == 255) bucketBase[nB] = smem[255];
}

#define SCAT_CHUNK 2048
__global__ __launch_bounds__(256) void bucket_scatter_kernel(const int* __restrict__ src,
    const int* __restrict__ dst, int* __restrict__ bucketCursor,
    uint32_t* __restrict__ bucketBuf, int E) {
  __shared__ int h[256];
  __shared__ int g[256];
  __shared__ int c[256];
  const int t = threadIdx.x;
  const int base = blockIdx.x * SCAT_CHUNK;
  const int end = min(base + SCAT_CHUNK, E);
  h[t] = 0;
  __syncthreads();
  for (int i = base + t; i < end; i += 256)
    atomicAdd(&h[dst[i] >> 8], 1);
  __syncthreads();
  if (h[t]) g[t] = atomicAdd(&bucketCursor[t], h[t]);
  c[t] = 0;
  __syncthreads();
  for (int i = base + t; i < end; i += 256) {
    const int d = dst[i];
    const int b = d >> 8;
    const int ticket = atomicAdd(&c[b], 1);
    bucketBuf[g[b] + ticket] = (uint32_t)src[i] | ((uint32_t)(d & 255) << 16);
  }
}

// ---------------- agg1: block = bucket, edge-parallel LDS accumulation ----------------
// acc stride 97 (f32): bank(ld*97+f) = (ld+f)%32 -> distinct ld => distinct banks.
#define AP 97
__global__ __launch_bounds__(256) void agg1_bucket_kernel(const uint16_t* __restrict__ xb,
    const uint32_t* __restrict__ bucketBuf, const int* __restrict__ bucketBase,
    uint16_t* __restrict__ AGGb, int N) {
  __shared__ float acc[256 * AP];   // 99328 B
  __shared__ int deg[256];
  const int t = threadIdx.x;
  const int b = blockIdx.x;
  for (int i = t; i < 256 * AP; i += 256) acc[i] = 0.f;
  deg[t] = 0;
  __syncthreads();

  const int beg = bucketBase[b], end = bucketBase[b + 1];
  for (int i = beg + t; i < end; i += 256) {
    const uint32_t u = bucketBuf[i];
    const int s = u & 0xFFFF;
    const int ld = (u >> 16) & 255;
    const uint16_t* xr = xb + (size_t)s * IN_DIM;
    // 12 x uint4 (16B = 8 bf16): v[q] covers features 8q..8q+7 (whole 96-row)
    uint4 v[12];
#pragma unroll
    for (int q = 0; q < 12; ++q) v[q] = *(const uint4*)(xr + q * 8);
    atomicAdd(&deg[ld], 1);
    float* row = &acc[ld * AP];
    __builtin_amdgcn_sched_barrier(0);
#pragma unroll
    for (int q = 0; q < 12; ++q) {
      const int f = q * 8;
      atomicAdd(&row[f + 0], bflo(v[q].x)); atomicAdd(&row[f + 1], bfhi(v[q].x));
      atomicAdd(&row[f + 2], bflo(v[q].y)); atomicAdd(&row[f + 3], bfhi(v[q].y));
      atomicAdd(&row[f + 4], bflo(v[q].z)); atomicAdd(&row[f + 5], bfhi(v[q].z));
      atomicAdd(&row[f + 6], bflo(v[q].w)); atomicAdd(&row[f + 7], bfhi(v[q].w));
    }
  }
  __syncthreads();

  const int node = (b << 8) + t;
  if (node < N) {
    const int d = deg[t];
    const float inv = 1.0f / (float)(d > 1 ? d : 1);
    const float* row = &acc[t * AP];
    uint16_t* orow = AGGb + (size_t)node * IN_DIM;
#pragma unroll
    for (int q = 0; q < 12; ++q) {
      const int f = q * 8;
      uint4 o;
      o.x = (uint32_t)f2bf(row[f + 0] * inv) | ((uint32_t)f2bf(row[f + 1] * inv) << 16);
      o.y = (uint32_t)f2bf(row[f + 2] * inv) | ((uint32_t)f2bf(row[f + 3] * inv) << 16);
      o.z = (uint32_t)f2bf(row[f + 4] * inv) | ((uint32_t)f2bf(row[f + 5] * inv) << 16);
      o.w = (uint32_t)f2bf(row[f + 6] * inv) | ((uint32_t)f2bf(row[f + 7] * inv) << 16);
      *(uint4*)(orow + f) = o;
    }
  }
}

// ---------------- final: block = bucket, edge-parallel over T2b ----------------
#define FP 65
__global__ __launch_bounds__(256) void final_bucket_kernel(const uint16_t* __restrict__ T2b,
    const float* __restrict__ R2, const uint32_t* __restrict__ bucketBuf,
    const int* __restrict__ bucketBase, float* __restrict__ out, int N) {
  __shared__ float acc[256 * FP];   // 66560 B
  __shared__ int deg[256];
  const int t = threadIdx.x;
  const int b = blockIdx.x;
  for (int i = t; i < 256 * FP; i += 256) acc[i] = 0.f;
  deg[t] = 0;
  __syncthreads();

  const int beg = bucketBase[b], end = bucketBase[b + 1];
  for (int i = beg + t; i < end; i += 256) {
    const uint32_t u = bucketBuf[i];
    const int s = u & 0xFFFF;
    const int ld = (u >> 16) & 255;
    const uint16_t* tr = T2b + (size_t)s * 64;
    uint4 v[8];
#pragma unroll
    for (int q = 0; q < 8; ++q) v[q] = *(const uint4*)(tr + q * 8);
    atomicAdd(&deg[ld], 1);
    float* row = &acc[ld * FP];
    __builtin_amdgcn_sched_barrier(0);
#pragma unroll
    for (int q = 0; q < 8; ++q) {
      const int f = q * 8;
      atomicAdd(&row[f + 0], bflo(v[q].x)); atomicAdd(&row[f + 1], bfhi(v[q].x));
      atomicAdd(&row[f + 2], bflo(v[q].y)); atomicAdd(&row[f + 3], bfhi(v[q].y));
      atomicAdd(&row[f + 4], bflo(v[q].z)); atomicAdd(&row[f + 5], bfhi(v[q].z));
      atomicAdd(&row[f + 6], bflo(v[q].w)); atomicAdd(&row[f + 7], bfhi(v[q].w));
    }
  }
  __syncthreads();

  const int node = (b << 8) + t;
  if (node < N) {
    const int d = deg[t];
    const float inv = 1.0f / (float)(d > 1 ? d : 1);
    const float* row = &acc[t * FP];
    const float* rr = R2 + (size_t)node * 64;
    float* orow = out + (size_t)node * 64;
#pragma unroll
    for (int q = 0; q < 16; ++q) {
      const int f = q * 4;
      float4 r = *(const float4*)(rr + f);
      float4 o;
      o.x = row[f + 0] * inv + r.x;
      o.y = row[f + 1] * inv + r.y;
      o.z = row[f + 2] * inv + r.z;
      o.w = row[f + 3] * inv + r.w;
      *(float4*)(orow + f) = o;
    }
  }
}

// ---------------- fused MFMA GEMM1+GEMM2, B staged in LDS (R10) ----------------
#define SP1 200
#define SP2 136
#define HP 136
__global__ __launch_bounds__(256) void gemm12_kernel(
    const uint16_t* __restrict__ AGGb, const uint16_t* __restrict__ xb,
    const uint16_t* __restrict__ S1t, const uint16_t* __restrict__ S2t,
    const float* __restrict__ b1, const float* __restrict__ b2,
    uint16_t* __restrict__ T2b, float* __restrict__ R2, int M) {
  __shared__ uint16_t BS[128 * SP1];
  __shared__ uint16_t Hs[64 * HP];
  const int tid = threadIdx.x;
  const int wv = tid >> 6;
  const int lane = tid & 63;
  const int m16 = lane & 15;
  const int quad = lane >> 4;
  const int rowBase = blockIdx.x * 64 + wv * 16;
  int arow = rowBase + m16;
  if (arow >= M) arow = M - 1;
  const int kq = quad * 8;

#pragma unroll
  for (int i = 0; i < 12; ++i) {
    const int idx8 = tid + i * 256;
    const int col = idx8 / 24;
    const int k8 = (idx8 - col * 24) * 8;
    const bf16x8 v = *(const bf16x8*)(S1t + (size_t)idx8 * 8);
    *(bf16x8*)&BS[col * SP1 + k8] = v;
  }
  bf16x8 a1f[6];
#pragma unroll
  for (int s = 0; s < 3; ++s)
    a1f[s] = *(const bf16x8*)(AGGb + (size_t)arow * IN_DIM + s * 32 + kq);
#pragma unroll
  for (int s = 0; s < 3; ++s)
    a1f[3 + s] = *(const bf16x8*)(xb + (size_t)arow * IN_DIM + s * 32 + kq);
  __syncthreads();

  f32x4 acc1[8];
#pragma unroll
  for (int cf = 0; cf < 8; ++cf) acc1[cf] = (f32x4){0.f, 0.f, 0.f, 0.f};
#pragma unroll
  for (int s = 0; s < 6; ++s) {
#pragma unroll
    for (int cf = 0; cf < 8; ++cf) {
      const bf16x8 b = *(const bf16x8*)&BS[(cf * 16 + m16) * SP1 + s * 32 + kq];
      acc1[cf] = __builtin_amdgcn_mfma_f32_16x16x32_bf16(a1f[s], b, acc1[cf], 0, 0, 0);
    }
  }

#pragma unroll
  for (int cf = 0; cf < 8; ++cf) {
    const int col = cf * 16 + m16;
    const float bias = b1[col];
#pragma unroll
    for (int r = 0; r < 4; ++r) {
      const float v = fmaxf(acc1[cf][r] + bias, 0.f);
      Hs[(wv * 16 + quad * 4 + r) * HP + col] = f2bf(v);
    }
  }
  __syncthreads();

#pragma unroll
  for (int i = 0; i < 8; ++i) {
    const int idx8 = tid + i * 256;
    const int col = idx8 >> 4;
    const int k8 = (idx8 & 15) * 8;
    const bf16x8 v = *(const bf16x8*)(S2t + (size_t)idx8 * 8);
    *(bf16x8*)&BS[col * SP2 + k8] = v;
  }
  __syncthreads();

  f32x4 acc2[8];
#pragma unroll
  for (int cf = 0; cf < 8; ++cf) acc2[cf] = (f32x4){0.f, 0.f, 0.f, 0.f};
#pragma unroll
  for (int s = 0; s < 4; ++s) {
    const bf16x8 a = *(const bf16x8*)&Hs[(wv * 16 + m16) * HP + s * 32 + kq];
#pragma unroll
    for (int cf = 0; cf < 8; ++cf) {
      const bf16x8 b = *(const bf16x8*)&BS[(cf * 16 + m16) * SP2 + s * 32 + kq];
      acc2[cf] = __builtin_amdgcn_mfma_f32_16x16x32_bf16(a, b, acc2[cf], 0, 0, 0);
    }
  }

#pragma unroll
  for (int cf = 0; cf < 8; ++cf) {
    const int col = cf * 16 + m16;
#pragma unroll
    for (int r = 0; r < 4; ++r) {
      const int row = rowBase + quad * 4 + r;
      if (row < M) {
        const float v = acc2[cf][r];
        if (col < 64) {
          T2b[(size_t)row * 64 + col] = f2bf(v);
        } else {
          R2[(size_t)row * 64 + (col - 64)] = v + b2[col - 64];
        }
      }
    }
  }
}

extern "C" void kernel_launch(void* const* d_in, const int* in_sizes, int n_in,
                              void* d_out, int out_size, void* d_ws, size_t ws_size,
                              hipStream_t stream) {
  const float* x   = (const float*)d_in[0];
  const int*   ei  = (const int*)d_in[1];
  const float* w1l = (const float*)d_in[2];
  const float* b1  = (const float*)d_in[3];
  const float* w1r = (const float*)d_in[4];
  const float* w2l = (const float*)d_in[5];
  const float* b2  = (const float*)d_in[6];
  const float* w2r = (const float*)d_in[7];
  float* out = (float*)d_out;

  const int N = in_sizes[0] / IN_DIM;   // 50000
  const int E = in_sizes[1] / 2;        // 800000
  const int* src = ei;
  const int* dst = ei + E;
  const int NB = (N + 255) >> 8;        // 196 buckets

  // ---- workspace carve (AGGb DISJOINT from T2b/R2 — round-7 bug) ----
  char* p = (char*)d_ws;
  uint16_t* AGGb = (uint16_t*)p; p += alignUp((size_t)N * IN_DIM * sizeof(uint16_t), 256);
  uint16_t* T2b  = (uint16_t*)p; p += alignUp((size_t)N * 64 * sizeof(uint16_t), 256);
  float* R2      = (float*)p;    p += alignUp((size_t)N * 64 * sizeof(float), 256);
  uint16_t* xb = (uint16_t*)p; p += alignUp((size_t)N * IN_DIM * sizeof(uint16_t), 256);
  uint16_t* S1t = (uint16_t*)p; p += alignUp(NS1 * sizeof(uint16_t), 256);
  uint16_t* S2t = (uint16_t*)p; p += alignUp(NS2 * sizeof(uint16_t), 256);
  uint32_t* bucketBuf = (uint32_t*)p; p += alignUp((size_t)E * sizeof(uint32_t), 256);
  int* bucketPart = (int*)p;   p += alignUp(CNT_BLOCKS * 256 * sizeof(int), 256);
  int* bucketBase = (int*)p;   p += alignUp(257 * sizeof(int), 256);
  int* bucketCursor = (int*)p; p += alignUp(256 * sizeof(int), 256);
  (void)ws_size; (void)n_in; (void)out_size;

  const int total4 = N * IN_DIM / 4;
  const int prepThreads = NS1 + NS2 + total4;
  const int prepBlocks = (prepThreads + 255) / 256;
  count_prep_kernel<<<CNT_BLOCKS + prepBlocks, 256, 0, stream>>>(
      dst, bucketPart, E, x, w1l, w1r, w2l, w2r, S1t, S2t, xb, total4);
  bucket_scan_kernel<<<1, 256, 0, stream>>>(bucketPart, bucketBase, bucketCursor, NB);
  bucket_scatter_kernel<<<(E + SCAT_CHUNK - 1) / SCAT_CHUNK, 256, 0, stream>>>(
      src, dst, bucketCursor, bucketBuf, E);

  agg1_bucket_kernel<<<NB, 256, 0, stream>>>(xb, bucketBuf, bucketBase, AGGb, N);

  const int gemmBlocks = (N + 63) / 64;
  gemm12_kernel<<<gemmBlocks, 256, 0, stream>>>(AGGb, xb, S1t, S2t, b1, b2, T2b, R2, N);

  final_bucket_kernel<<<NB, 256, 0, stream>>>(T2b, R2, bucketBuf, bucketBase, out, N);
}

// Round 15
// 214.094 us; speedup vs baseline: 4.7151x; 4.7151x over previous
//
#include <hip/hip_runtime.h>
#include <cstdint>
#include <cstddef>

// BinSAGE: 2-layer GraphSAGE, sign-binarized weights. MFMA bf16 + bucket CSR.
// N=50000, E=800000, dims 96 -> 128 -> 64.
// R14 lesson: edge-parallel LDS-atomic aggregation is LDS-atomic-bound (528us,
//   VALUBusy 0.6%) — REVERTED to R12 subgroup-CSR gathers (register accum).
// R15 change: gathers are at a hardware outstanding-miss ceiling (R11/R12
//   neutral), so time ~ miss BYTES. Row-scaled int8 payloads (error parity
//   with bf16): xq[N,96]i8+xscale (agg1: 192->96 B/edge), T2q[N,64]i8+tscale
//   (final: 128->68 B/edge), quantized in gemm12 epilogue via shfl row-max.
// R9 lesson: GEMM B LDS-staged. R7 lesson: no aliasing across fused phases.

#define N_NODES 50000
#define IN_DIM 96
#define HID 128
#define OUT_DIM 64
#define CNT_BLOCKS 64

typedef __attribute__((ext_vector_type(8))) short bf16x8;
typedef __attribute__((ext_vector_type(4))) float f32x4;

static inline size_t alignUp(size_t v, size_t a) { return (v + a - 1) & ~(a - 1); }

__device__ __forceinline__ uint16_t f2bf(float f) {
  uint32_t u = __float_as_uint(f);
  return (uint16_t)((u + 0x7FFF + ((u >> 16) & 1)) >> 16);
}
__device__ __forceinline__ float bflo(uint32_t v) { return __uint_as_float(v << 16); }
__device__ __forceinline__ float bfhi(uint32_t v) { return __uint_as_float(v & 0xFFFF0000u); }
__device__ __forceinline__ uint16_t sgnbf(float w) {
  return (w > 0.f) ? (uint16_t)0x3F80 : ((w < 0.f) ? (uint16_t)0xBF80 : (uint16_t)0);
}
__device__ __forceinline__ float i8f(uint32_t w, int b) {
  return (float)(int8_t)((w >> (8 * b)) & 0xFF);
}

#define NS1 (128 * 192)
#define NS2 (128 * 128)

// ---------- merged: bucket count + sign matrices + xb bf16 + xq int8 ----------
__global__ __launch_bounds__(256) void count_prep_kernel(const int* __restrict__ dst,
    int* __restrict__ bucketPart, int E,
    const float* __restrict__ x,
    const float* __restrict__ w1l, const float* __restrict__ w1r,
    const float* __restrict__ w2l, const float* __restrict__ w2r,
    uint16_t* __restrict__ S1t, uint16_t* __restrict__ S2t,
    uint16_t* __restrict__ xb, int total4,
    int8_t* __restrict__ xq, float* __restrict__ xscale, int N) {
  __shared__ int h[256];
  const int t = threadIdx.x;
  if (blockIdx.x < CNT_BLOCKS) {
    h[t] = 0;
    __syncthreads();
    const int stride = CNT_BLOCKS * 256;
    for (int i = blockIdx.x * 256 + t; i < E; i += stride)
      atomicAdd(&h[dst[i] >> 8], 1);
    __syncthreads();
    bucketPart[blockIdx.x * 256 + t] = h[t];
    return;
  }
  const int idx = (blockIdx.x - CNT_BLOCKS) * 256 + t;
  if (idx < NS1) {
    int n = idx / 192, k = idx - n * 192;
    float w = (k < 96) ? w1l[n * 96 + k] : w1r[n * 96 + (k - 96)];
    S1t[idx] = sgnbf(w);
  } else if (idx < NS1 + NS2) {
    int i2 = idx - NS1;
    int n = i2 >> 7, k = i2 & 127;
    float w = (n < 64) ? w2l[n * 128 + k] : w2r[(n - 64) * 128 + k];
    S2t[i2] = sgnbf(w);
  } else if (idx < NS1 + NS2 + total4) {
    int i = idx - NS1 - NS2;
    float4 v = *(const float4*)(x + (size_t)i * 4);
    uint32_t p0 = (uint32_t)f2bf(v.x) | ((uint32_t)f2bf(v.y) << 16);
    uint32_t p1 = (uint32_t)f2bf(v.z) | ((uint32_t)f2bf(v.w) << 16);
    *(uint2*)(xb + (size_t)i * 4) = make_uint2(p0, p1);
  } else {
    const int row = idx - NS1 - NS2 - total4;
    if (row < N) {
      const float* xr = x + (size_t)row * IN_DIM;
      float mx = 0.f;
      for (int q = 0; q < 24; ++q) {
        float4 v = *(const float4*)(xr + q * 4);
        mx = fmaxf(mx, fmaxf(fmaxf(fabsf(v.x), fabsf(v.y)), fmaxf(fabsf(v.z), fabsf(v.w))));
      }
      mx = fmaxf(mx, 1e-8f);
      const float is = 127.f / mx;
      xscale[row] = mx / 127.f;
      int8_t* orow = xq + (size_t)row * IN_DIM;
      for (int g = 0; g < 6; ++g) {  // 6 x 16 bytes
        uint32_t w[4];
#pragma unroll
        for (int c = 0; c < 4; ++c) {
          float4 v = *(const float4*)(xr + g * 16 + c * 4);
          uint32_t b0 = (uint32_t)(uint8_t)(int8_t)__float2int_rn(v.x * is);
          uint32_t b1 = (uint32_t)(uint8_t)(int8_t)__float2int_rn(v.y * is);
          uint32_t b2 = (uint32_t)(uint8_t)(int8_t)__float2int_rn(v.z * is);
          uint32_t b3 = (uint32_t)(uint8_t)(int8_t)__float2int_rn(v.w * is);
          w[c] = b0 | (b1 << 8) | (b2 << 16) | (b3 << 24);
        }
        *(uint4*)(orow + g * 16) = make_uint4(w[0], w[1], w[2], w[3]);
      }
    }
  }
}

// 1 block: column-sum partials -> scan -> bases/cursors.
__global__ __launch_bounds__(256) void bucket_scan_kernel(const int* __restrict__ bucketPart,
    int* __restrict__ bucketBase, int* __restrict__ bucketCursor, int* __restrict__ rowptr,
    int nB, int N) {
  __shared__ int smem[256];
  const int t = threadIdx.x;
  int v = 0;
  for (int b = 0; b < CNT_BLOCKS; ++b) v += bucketPart[b * 256 + t];
  if (t >= nB) v = 0;
  smem[t] = v;
  __syncthreads();
  for (int off = 1; off < 256; off <<= 1) {
    int u = (t >= off) ? smem[t - off] : 0;
    __syncthreads();
    smem[t] += u;
    __syncthreads();
  }
  if (t < nB) {
    const int excl = smem[t] - v;
    bucketBase[t] = excl;
    bucketCursor[t] = excl;
  }
  if (t == 255) {
    bucketBase[nB] = smem[255];
    rowptr[N] = smem[255];
  }
}

#define SCAT_CHUNK 2048
__global__ __launch_bounds__(256) void bucket_scatter_kernel(const int* __restrict__ src,
    const int* __restrict__ dst, int* __restrict__ bucketCursor,
    uint32_t* __restrict__ bucketBuf, int E) {
  __shared__ int h[256];
  __shared__ int g[256];
  __shared__ int c[256];
  const int t = threadIdx.x;
  const int base = blockIdx.x * SCAT_CHUNK;
  const int end = min(base + SCAT_CHUNK, E);
  h[t] = 0;
  __syncthreads();
  for (int i = base + t; i < end; i += 256)
    atomicAdd(&h[dst[i] >> 8], 1);
  __syncthreads();
  if (h[t]) g[t] = atomicAdd(&bucketCursor[t], h[t]);
  c[t] = 0;
  __syncthreads();
  for (int i = base + t; i < end; i += 256) {
    const int d = dst[i];
    const int b = d >> 8;
    const int ticket = atomicAdd(&c[b], 1);
    bucketBuf[g[b] + ticket] = (uint32_t)src[i] | ((uint32_t)(d & 255) << 16);
  }
}

__global__ __launch_bounds__(256) void bucket_build_kernel(const uint32_t* __restrict__ bucketBuf,
    const int* __restrict__ bucketBase, int* __restrict__ rowptr,
    uint16_t* __restrict__ adj16, int N) {
  __shared__ int h[256];
  __shared__ int s[256];
  __shared__ int cur[256];
  const int t = threadIdx.x;
  const int b = blockIdx.x;
  const int nodeBase = b << 8;
  const int beg = bucketBase[b], end = bucketBase[b + 1];
  const int m = end - beg;
  h[t] = 0;
  __syncthreads();
  for (int i = t; i < m; i += 256)
    atomicAdd(&h[(bucketBuf[beg + i] >> 16) & 255], 1);
  __syncthreads();
  const int d = h[t];
  s[t] = d;
  __syncthreads();
  for (int off = 1; off < 256; off <<= 1) {
    int u = (t >= off) ? s[t - off] : 0;
    __syncthreads();
    s[t] += u;
    __syncthreads();
  }
  const int excl = s[t] - d;
  const int node = nodeBase + t;
  if (node < N) rowptr[node] = beg + excl;
  cur[t] = excl;
  __syncthreads();
  for (int i = t; i < m; i += 256) {
    const uint32_t u = bucketBuf[beg + i];
    const int ld = (u >> 16) & 255;
    const int ticket = atomicAdd(&cur[ld], 1);
    adj16[beg + ticket] = (uint16_t)(u & 0xFFFFu);
  }
}

// ---------- agg1: subgroup(16)=node, 8-edge batches, int8 payload ----------
__global__ __launch_bounds__(256) void agg1_kernel(const int8_t* __restrict__ xq,
    const float* __restrict__ xscale, const uint16_t* __restrict__ adj16,
    const int* __restrict__ rowptr, uint16_t* __restrict__ AGGb, int nNodes) {
  const int sg = threadIdx.x >> 4;
  const int j = threadIdx.x & 15;
  const int n = blockIdx.x * 16 + sg;
  if (n >= nNodes) return;
  const int beg = rowptr[n], end = rowptr[n + 1];
  const bool act = j < 12;
  const int foff = j * 8;  // byte offset: feats 8j..8j+7
  float a0 = 0.f, a1 = 0.f, a2 = 0.f, a3 = 0.f, a4 = 0.f, a5 = 0.f, a6 = 0.f, a7 = 0.f;

  int e = beg;
  if ((e & 1) && e < end) {
    const int s = adj16[e];
    const float sc = xscale[s];
    uint2 v = act ? *(const uint2*)(xq + (size_t)s * IN_DIM + foff) : make_uint2(0u, 0u);
    a0 += sc * i8f(v.x, 0); a1 += sc * i8f(v.x, 1);
    a2 += sc * i8f(v.x, 2); a3 += sc * i8f(v.x, 3);
    a4 += sc * i8f(v.y, 0); a5 += sc * i8f(v.y, 1);
    a6 += sc * i8f(v.y, 2); a7 += sc * i8f(v.y, 3);
    ++e;
  }
  for (; e + 8 <= end; e += 8) {
    const uint32_t p0 = *(const uint32_t*)(adj16 + e);
    const uint32_t p1 = *(const uint32_t*)(adj16 + e + 2);
    const uint32_t p2 = *(const uint32_t*)(adj16 + e + 4);
    const uint32_t p3 = *(const uint32_t*)(adj16 + e + 6);
    const int s[8] = {(int)(p0 & 0xFFFF), (int)(p0 >> 16), (int)(p1 & 0xFFFF), (int)(p1 >> 16),
                      (int)(p2 & 0xFFFF), (int)(p2 >> 16), (int)(p3 & 0xFFFF), (int)(p3 >> 16)};
    uint2 v[8];
    float sc[8];
#pragma unroll
    for (int u = 0; u < 8; ++u) {
      sc[u] = xscale[s[u]];
      v[u] = act ? *(const uint2*)(xq + (size_t)s[u] * IN_DIM + foff) : make_uint2(0u, 0u);
    }
    __builtin_amdgcn_sched_barrier(0);
#pragma unroll
    for (int u = 0; u < 8; ++u) {
      a0 += sc[u] * i8f(v[u].x, 0); a1 += sc[u] * i8f(v[u].x, 1);
      a2 += sc[u] * i8f(v[u].x, 2); a3 += sc[u] * i8f(v[u].x, 3);
      a4 += sc[u] * i8f(v[u].y, 0); a5 += sc[u] * i8f(v[u].y, 1);
      a6 += sc[u] * i8f(v[u].y, 2); a7 += sc[u] * i8f(v[u].y, 3);
    }
  }
  for (; e < end; ++e) {
    const int s = adj16[e];
    const float sc = xscale[s];
    uint2 v = act ? *(const uint2*)(xq + (size_t)s * IN_DIM + foff) : make_uint2(0u, 0u);
    a0 += sc * i8f(v.x, 0); a1 += sc * i8f(v.x, 1);
    a2 += sc * i8f(v.x, 2); a3 += sc * i8f(v.x, 3);
    a4 += sc * i8f(v.y, 0); a5 += sc * i8f(v.y, 1);
    a6 += sc * i8f(v.y, 2); a7 += sc * i8f(v.y, 3);
  }
  if (act) {
    const int d = end - beg;
    const float inv = 1.0f / (float)(d > 1 ? d : 1);
    uint4 o;
    o.x = (uint32_t)f2bf(a0 * inv) | ((uint32_t)f2bf(a1 * inv) << 16);
    o.y = (uint32_t)f2bf(a2 * inv) | ((uint32_t)f2bf(a3 * inv) << 16);
    o.z = (uint32_t)f2bf(a4 * inv) | ((uint32_t)f2bf(a5 * inv) << 16);
    o.w = (uint32_t)f2bf(a6 * inv) | ((uint32_t)f2bf(a7 * inv) << 16);
    *(uint4*)(AGGb + (size_t)n * IN_DIM + foff) = o;
  }
}

// ---------- final: subgroup(16)=node; lane j covers feats 4j..4j+3 (u32 of T2q) ----------
__global__ __launch_bounds__(256) void final_kernel(const int8_t* __restrict__ T2q,
    const float* __restrict__ tscale, const float* __restrict__ R2,
    const uint16_t* __restrict__ adj16, const int* __restrict__ rowptr,
    float* __restrict__ out, int nNodes) {
  const int sg = threadIdx.x >> 4;
  const int j = threadIdx.x & 15;
  const int n = blockIdx.x * 16 + sg;
  if (n >= nNodes) return;
  const int beg = rowptr[n], end = rowptr[n + 1];
  const int foff = j * 4;
  float a0 = 0.f, a1 = 0.f, a2 = 0.f, a3 = 0.f;

  int e = beg;
  if ((e & 1) && e < end) {
    const int s = adj16[e];
    const float sc = tscale[s];
    const uint32_t v = *(const uint32_t*)(T2q + (size_t)s * 64 + foff);
    a0 += sc * i8f(v, 0); a1 += sc * i8f(v, 1); a2 += sc * i8f(v, 2); a3 += sc * i8f(v, 3);
    ++e;
  }
  for (; e + 8 <= end; e += 8) {
    const uint32_t p0 = *(const uint32_t*)(adj16 + e);
    const uint32_t p1 = *(const uint32_t*)(adj16 + e + 2);
    const uint32_t p2 = *(const uint32_t*)(adj16 + e + 4);
    const uint32_t p3 = *(const uint32_t*)(adj16 + e + 6);
    const int s[8] = {(int)(p0 & 0xFFFF), (int)(p0 >> 16), (int)(p1 & 0xFFFF), (int)(p1 >> 16),
                      (int)(p2 & 0xFFFF), (int)(p2 >> 16), (int)(p3 & 0xFFFF), (int)(p3 >> 16)};
    uint32_t v[8];
    float sc[8];
#pragma unroll
    for (int u = 0; u < 8; ++u) {
      sc[u] = tscale[s[u]];
      v[u] = *(const uint32_t*)(T2q + (size_t)s[u] * 64 + foff);
    }
    __builtin_amdgcn_sched_barrier(0);
#pragma unroll
    for (int u = 0; u < 8; ++u) {
      a0 += sc[u] * i8f(v[u], 0); a1 += sc[u] * i8f(v[u], 1);
      a2 += sc[u] * i8f(v[u], 2); a3 += sc[u] * i8f(v[u], 3);
    }
  }
  for (; e < end; ++e) {
    const int s = adj16[e];
    const float sc = tscale[s];
    const uint32_t v = *(const uint32_t*)(T2q + (size_t)s * 64 + foff);
    a0 += sc * i8f(v, 0); a1 += sc * i8f(v, 1); a2 += sc * i8f(v, 2); a3 += sc * i8f(v, 3);
  }
  const int d = end - beg;
  const float inv = 1.0f / (float)(d > 1 ? d : 1);
  const float4 r = *(const float4*)(R2 + (size_t)n * 64 + foff);
  float4 o;
  o.x = a0 * inv + r.x;
  o.y = a1 * inv + r.y;
  o.z = a2 * inv + r.z;
  o.w = a3 * inv + r.w;
  *(float4*)(out + (size_t)n * 64 + foff) = o;
}

// ---------- fused MFMA GEMM1+GEMM2, B staged in LDS; T2 -> int8 row-scaled ----------
#define SP1 200
#define SP2 136
#define HP 136
__global__ __launch_bounds__(256) void gemm12_kernel(
    const uint16_t* __restrict__ AGGb, const uint16_t* __restrict__ xb,
    const uint16_t* __restrict__ S1t, const uint16_t* __restrict__ S2t,
    const float* __restrict__ b1, const float* __restrict__ b2,
    int8_t* __restrict__ T2q, float* __restrict__ tscale, float* __restrict__ R2, int M) {
  __shared__ uint16_t BS[128 * SP1];
  __shared__ uint16_t Hs[64 * HP];
  const int tid = threadIdx.x;
  const int wv = tid >> 6;
  const int lane = tid & 63;
  const int m16 = lane & 15;
  const int quad = lane >> 4;
  const int rowBase = blockIdx.x * 64 + wv * 16;
  int arow = rowBase + m16;
  if (arow >= M) arow = M - 1;
  const int kq = quad * 8;

#pragma unroll
  for (int i = 0; i < 12; ++i) {
    const int idx8 = tid + i * 256;
    const int col = idx8 / 24;
    const int k8 = (idx8 - col * 24) * 8;
    const bf16x8 v = *(const bf16x8*)(S1t + (size_t)idx8 * 8);
    *(bf16x8*)&BS[col * SP1 + k8] = v;
  }
  bf16x8 a1f[6];
#pragma unroll
  for (int s = 0; s < 3; ++s)
    a1f[s] = *(const bf16x8*)(AGGb + (size_t)arow * IN_DIM + s * 32 + kq);
#pragma unroll
  for (int s = 0; s < 3; ++s)
    a1f[3 + s] = *(const bf16x8*)(xb + (size_t)arow * IN_DIM + s * 32 + kq);
  __syncthreads();

  f32x4 acc1[8];
#pragma unroll
  for (int cf = 0; cf < 8; ++cf) acc1[cf] = (f32x4){0.f, 0.f, 0.f, 0.f};
#pragma unroll
  for (int s = 0; s < 6; ++s) {
#pragma unroll
    for (int cf = 0; cf < 8; ++cf) {
      const bf16x8 b = *(const bf16x8*)&BS[(cf * 16 + m16) * SP1 + s * 32 + kq];
      acc1[cf] = __builtin_amdgcn_mfma_f32_16x16x32_bf16(a1f[s], b, acc1[cf], 0, 0, 0);
    }
  }

#pragma unroll
  for (int cf = 0; cf < 8; ++cf) {
    const int col = cf * 16 + m16;
    const float bias = b1[col];
#pragma unroll
    for (int r = 0; r < 4; ++r) {
      const float v = fmaxf(acc1[cf][r] + bias, 0.f);
      Hs[(wv * 16 + quad * 4 + r) * HP + col] = f2bf(v);
    }
  }
  __syncthreads();

#pragma unroll
  for (int i = 0; i < 8; ++i) {
    const int idx8 = tid + i * 256;
    const int col = idx8 >> 4;
    const int k8 = (idx8 & 15) * 8;
    const bf16x8 v = *(const bf16x8*)(S2t + (size_t)idx8 * 8);
    *(bf16x8*)&BS[col * SP2 + k8] = v;
  }
  __syncthreads();

  f32x4 acc2[8];
#pragma unroll
  for (int cf = 0; cf < 8; ++cf) acc2[cf] = (f32x4){0.f, 0.f, 0.f, 0.f};
#pragma unroll
  for (int s = 0; s < 4; ++s) {
    const bf16x8 a = *(const bf16x8*)&Hs[(wv * 16 + m16) * HP + s * 32 + kq];
#pragma unroll
    for (int cf = 0; cf < 8; ++cf) {
      const bf16x8 b = *(const bf16x8*)&BS[(cf * 16 + m16) * SP2 + s * 32 + kq];
      acc2[cf] = __builtin_amdgcn_mfma_f32_16x16x32_bf16(a, b, acc2[cf], 0, 0, 0);
    }
  }

  // epilogue: cols 0..63 (cf 0..3) -> T2q int8 row-scaled; cols 64..127 -> R2 f32 (+b2)
#pragma unroll
  for (int r = 0; r < 4; ++r) {
    float m = 0.f;
#pragma unroll
    for (int cf = 0; cf < 4; ++cf) m = fmaxf(m, fabsf(acc2[cf][r]));
#pragma unroll
    for (int w = 1; w < 16; w <<= 1) m = fmaxf(m, __shfl_xor(m, w));
    m = fmaxf(m, 1e-8f);
    const float is = 127.f / m;
    const int row = rowBase + quad * 4 + r;
    if (row < M) {
#pragma unroll
      for (int cf = 0; cf < 4; ++cf) {
        const int q = __float2int_rn(acc2[cf][r] * is);
        T2q[(size_t)row * 64 + cf * 16 + m16] = (int8_t)q;
      }
      if (m16 == 0) tscale[row] = m / 127.f;
    }
  }
#pragma unroll
  for (int cf = 4; cf < 8; ++cf) {
    const int col = cf * 16 + m16;
#pragma unroll
    for (int r = 0; r < 4; ++r) {
      const int row = rowBase + quad * 4 + r;
      if (row < M) R2[(size_t)row * 64 + (col - 64)] = acc2[cf][r] + b2[col - 64];
    }
  }
}

extern "C" void kernel_launch(void* const* d_in, const int* in_sizes, int n_in,
                              void* d_out, int out_size, void* d_ws, size_t ws_size,
                              hipStream_t stream) {
  const float* x   = (const float*)d_in[0];
  const int*   ei  = (const int*)d_in[1];
  const float* w1l = (const float*)d_in[2];
  const float* b1  = (const float*)d_in[3];
  const float* w1r = (const float*)d_in[4];
  const float* w2l = (const float*)d_in[5];
  const float* b2  = (const float*)d_in[6];
  const float* w2r = (const float*)d_in[7];
  float* out = (float*)d_out;

  const int N = in_sizes[0] / IN_DIM;   // 50000
  const int E = in_sizes[1] / 2;        // 800000
  const int* src = ei;
  const int* dst = ei + E;
  const int NB = (N + 255) >> 8;        // 196 buckets

  // ---- workspace carve (all regions DISJOINT) ----
  char* p = (char*)d_ws;
  uint16_t* AGGb = (uint16_t*)p; p += alignUp((size_t)N * IN_DIM * sizeof(uint16_t), 256);
  int8_t* T2q = (int8_t*)p;      p += alignUp((size_t)N * 64, 256);
  float* tscale = (float*)p;     p += alignUp((size_t)N * sizeof(float), 256);
  float* R2 = (float*)p;         p += alignUp((size_t)N * 64 * sizeof(float), 256);
  uint16_t* xb = (uint16_t*)p;   p += alignUp((size_t)N * IN_DIM * sizeof(uint16_t), 256);
  int8_t* xq = (int8_t*)p;       p += alignUp((size_t)N * IN_DIM, 256);
  float* xscale = (float*)p;     p += alignUp((size_t)N * sizeof(float), 256);
  uint16_t* S1t = (uint16_t*)p;  p += alignUp(NS1 * sizeof(uint16_t), 256);
  uint16_t* S2t = (uint16_t*)p;  p += alignUp(NS2 * sizeof(uint16_t), 256);
  int* rowptr = (int*)p;         p += alignUp((size_t)(N + 1) * sizeof(int), 256);
  uint16_t* adj16 = (uint16_t*)p; p += alignUp((size_t)E * sizeof(uint16_t), 256);
  uint32_t* bucketBuf = (uint32_t*)p; p += alignUp((size_t)E * sizeof(uint32_t), 256);
  int* bucketPart = (int*)p;     p += alignUp(CNT_BLOCKS * 256 * sizeof(int), 256);
  int* bucketBase = (int*)p;     p += alignUp(257 * sizeof(int), 256);
  int* bucketCursor = (int*)p;   p += alignUp(256 * sizeof(int), 256);
  (void)ws_size; (void)n_in; (void)out_size;

  const int total4 = N * IN_DIM / 4;
  const int prepThreads = NS1 + NS2 + total4 + N;
  const int prepBlocks = (prepThreads + 255) / 256;
  count_prep_kernel<<<CNT_BLOCKS + prepBlocks, 256, 0, stream>>>(
      dst, bucketPart, E, x, w1l, w1r, w2l, w2r, S1t, S2t, xb, total4, xq, xscale, N);
  bucket_scan_kernel<<<1, 256, 0, stream>>>(bucketPart, bucketBase, bucketCursor, rowptr, NB, N);
  bucket_scatter_kernel<<<(E + SCAT_CHUNK - 1) / SCAT_CHUNK, 256, 0, stream>>>(
      src, dst, bucketCursor, bucketBuf, E);
  bucket_build_kernel<<<NB, 256, 0, stream>>>(bucketBuf, bucketBase, rowptr, adj16, N);

  const int nodeBlocks16 = (N + 15) / 16;
  agg1_kernel<<<nodeBlocks16, 256, 0, stream>>>(xq, xscale, adj16, rowptr, AGGb, N);

  const int gemmBlocks = (N + 63) / 64;
  gemm12_kernel<<<gemmBlocks, 256, 0, stream>>>(AGGb, xb, S1t, S2t, b1, b2,
                                                T2q, tscale, R2, N);

  final_kernel<<<nodeBlocks16, 256, 0, stream>>>(T2q, tscale, R2, adj16, rowptr, out, N);
}

// Round 16
// 189.850 us; speedup vs baseline: 5.3172x; 1.1277x over previous
//
#include <hip/hip_runtime.h>
#include <cstdint>
#include <cstddef>

// BinSAGE: 2-layer GraphSAGE, sign-binarized weights. MFMA bf16 + bucket CSR.
// N=50000, E=800000, dims 96 -> 128 -> 64.
// R15 lesson: per-row serial quantization in prep cost ~50us (uncoalesced
//   latency chain). R16: quantize with 16-lane subgroup per row (coalesced
//   float4 loads + shfl_xor max), quant region 256-aligned so subgroup
//   shuffles never cross a branch boundary.
// R15 theory under test: gathers are outstanding-miss-BYTE bound; int8
//   row-scaled payloads (xq 96B/edge, T2q 68B/edge) should ~halve them.
// R14 lesson: no LDS-atomic aggregation. R9: GEMM B LDS-staged. R7: no
//   aliasing across fused phases.

#define N_NODES 50000
#define IN_DIM 96
#define HID 128
#define OUT_DIM 64
#define CNT_BLOCKS 64

typedef __attribute__((ext_vector_type(8))) short bf16x8;
typedef __attribute__((ext_vector_type(4))) float f32x4;

static inline size_t alignUp(size_t v, size_t a) { return (v + a - 1) & ~(a - 1); }

__device__ __forceinline__ uint16_t f2bf(float f) {
  uint32_t u = __float_as_uint(f);
  return (uint16_t)((u + 0x7FFF + ((u >> 16) & 1)) >> 16);
}
__device__ __forceinline__ float bflo(uint32_t v) { return __uint_as_float(v << 16); }
__device__ __forceinline__ float bfhi(uint32_t v) { return __uint_as_float(v & 0xFFFF0000u); }
__device__ __forceinline__ uint16_t sgnbf(float w) {
  return (w > 0.f) ? (uint16_t)0x3F80 : ((w < 0.f) ? (uint16_t)0xBF80 : (uint16_t)0);
}
__device__ __forceinline__ float i8f(uint32_t w, int b) {
  return (float)(int8_t)((w >> (8 * b)) & 0xFF);
}

#define NS1 (128 * 192)
#define NS2 (128 * 128)

// ---------- merged: bucket count + sign matrices + xb bf16 + xq int8 ----------
// quantBase is 256-aligned; quant uses 16-lane subgroup per row.
__global__ __launch_bounds__(256) void count_prep_kernel(const int* __restrict__ dst,
    int* __restrict__ bucketPart, int E,
    const float* __restrict__ x,
    const float* __restrict__ w1l, const float* __restrict__ w1r,
    const float* __restrict__ w2l, const float* __restrict__ w2r,
    uint16_t* __restrict__ S1t, uint16_t* __restrict__ S2t,
    uint16_t* __restrict__ xb, int total4,
    int8_t* __restrict__ xq, float* __restrict__ xscale, int N, int quantBase) {
  __shared__ int h[256];
  const int t = threadIdx.x;
  if (blockIdx.x < CNT_BLOCKS) {
    h[t] = 0;
    __syncthreads();
    const int stride = CNT_BLOCKS * 256;
    for (int i = blockIdx.x * 256 + t; i < E; i += stride)
      atomicAdd(&h[dst[i] >> 8], 1);
    __syncthreads();
    bucketPart[blockIdx.x * 256 + t] = h[t];
    return;
  }
  const int idx = (blockIdx.x - CNT_BLOCKS) * 256 + t;
  if (idx < NS1) {
    int n = idx / 192, k = idx - n * 192;
    float w = (k < 96) ? w1l[n * 96 + k] : w1r[n * 96 + (k - 96)];
    S1t[idx] = sgnbf(w);
  } else if (idx < NS1 + NS2) {
    int i2 = idx - NS1;
    int n = i2 >> 7, k = i2 & 127;
    float w = (n < 64) ? w2l[n * 128 + k] : w2r[(n - 64) * 128 + k];
    S2t[i2] = sgnbf(w);
  } else if (idx < NS1 + NS2 + total4) {
    int i = idx - NS1 - NS2;
    float4 v = *(const float4*)(x + (size_t)i * 4);
    uint32_t p0 = (uint32_t)f2bf(v.x) | ((uint32_t)f2bf(v.y) << 16);
    uint32_t p1 = (uint32_t)f2bf(v.z) | ((uint32_t)f2bf(v.w) << 16);
    *(uint2*)(xb + (size_t)i * 4) = make_uint2(p0, p1);
  } else if (idx >= quantBase) {
    const int qi = idx - quantBase;
    const int row = qi >> 4;
    const int j = qi & 15;
    if (row < N) {
      const float* xr = x + (size_t)row * IN_DIM;
      const bool act = j < 12;
      float f[8];
      float mx = 0.f;
      if (act) {
        const float4 v0 = *(const float4*)(xr + j * 8);
        const float4 v1 = *(const float4*)(xr + j * 8 + 4);
        f[0] = v0.x; f[1] = v0.y; f[2] = v0.z; f[3] = v0.w;
        f[4] = v1.x; f[5] = v1.y; f[6] = v1.z; f[7] = v1.w;
#pragma unroll
        for (int q = 0; q < 8; ++q) mx = fmaxf(mx, fabsf(f[q]));
      }
#pragma unroll
      for (int w = 1; w < 16; w <<= 1) mx = fmaxf(mx, __shfl_xor(mx, w));
      mx = fmaxf(mx, 1e-8f);
      const float is = 127.f / mx;
      if (act) {
        uint32_t w0 = 0, w1 = 0;
#pragma unroll
        for (int q = 0; q < 4; ++q)
          w0 |= ((uint32_t)(uint8_t)(int8_t)__float2int_rn(f[q] * is)) << (8 * q);
#pragma unroll
        for (int q = 0; q < 4; ++q)
          w1 |= ((uint32_t)(uint8_t)(int8_t)__float2int_rn(f[4 + q] * is)) << (8 * q);
        *(uint2*)(xq + (size_t)row * IN_DIM + j * 8) = make_uint2(w0, w1);
      }
      if (j == 0) xscale[row] = mx / 127.f;
    }
  }
}

// 1 block: column-sum partials -> scan -> bases/cursors.
__global__ __launch_bounds__(256) void bucket_scan_kernel(const int* __restrict__ bucketPart,
    int* __restrict__ bucketBase, int* __restrict__ bucketCursor, int* __restrict__ rowptr,
    int nB, int N) {
  __shared__ int smem[256];
  const int t = threadIdx.x;
  int v = 0;
  for (int b = 0; b < CNT_BLOCKS; ++b) v += bucketPart[b * 256 + t];
  if (t >= nB) v = 0;
  smem[t] = v;
  __syncthreads();
  for (int off = 1; off < 256; off <<= 1) {
    int u = (t >= off) ? smem[t - off] : 0;
    __syncthreads();
    smem[t] += u;
    __syncthreads();
  }
  if (t < nB) {
    const int excl = smem[t] - v;
    bucketBase[t] = excl;
    bucketCursor[t] = excl;
  }
  if (t == 255) {
    bucketBase[nB] = smem[255];
    rowptr[N] = smem[255];
  }
}

#define SCAT_CHUNK 2048
__global__ __launch_bounds__(256) void bucket_scatter_kernel(const int* __restrict__ src,
    const int* __restrict__ dst, int* __restrict__ bucketCursor,
    uint32_t* __restrict__ bucketBuf, int E) {
  __shared__ int h[256];
  __shared__ int g[256];
  __shared__ int c[256];
  const int t = threadIdx.x;
  const int base = blockIdx.x * SCAT_CHUNK;
  const int end = min(base + SCAT_CHUNK, E);
  h[t] = 0;
  __syncthreads();
  for (int i = base + t; i < end; i += 256)
    atomicAdd(&h[dst[i] >> 8], 1);
  __syncthreads();
  if (h[t]) g[t] = atomicAdd(&bucketCursor[t], h[t]);
  c[t] = 0;
  __syncthreads();
  for (int i = base + t; i < end; i += 256) {
    const int d = dst[i];
    const int b = d >> 8;
    const int ticket = atomicAdd(&c[b], 1);
    bucketBuf[g[b] + ticket] = (uint32_t)src[i] | ((uint32_t)(d & 255) << 16);
  }
}

__global__ __launch_bounds__(256) void bucket_build_kernel(const uint32_t* __restrict__ bucketBuf,
    const int* __restrict__ bucketBase, int* __restrict__ rowptr,
    uint16_t* __restrict__ adj16, int N) {
  __shared__ int h[256];
  __shared__ int s[256];
  __shared__ int cur[256];
  const int t = threadIdx.x;
  const int b = blockIdx.x;
  const int nodeBase = b << 8;
  const int beg = bucketBase[b], end = bucketBase[b + 1];
  const int m = end - beg;
  h[t] = 0;
  __syncthreads();
  for (int i = t; i < m; i += 256)
    atomicAdd(&h[(bucketBuf[beg + i] >> 16) & 255], 1);
  __syncthreads();
  const int d = h[t];
  s[t] = d;
  __syncthreads();
  for (int off = 1; off < 256; off <<= 1) {
    int u = (t >= off) ? s[t - off] : 0;
    __syncthreads();
    s[t] += u;
    __syncthreads();
  }
  const int excl = s[t] - d;
  const int node = nodeBase + t;
  if (node < N) rowptr[node] = beg + excl;
  cur[t] = excl;
  __syncthreads();
  for (int i = t; i < m; i += 256) {
    const uint32_t u = bucketBuf[beg + i];
    const int ld = (u >> 16) & 255;
    const int ticket = atomicAdd(&cur[ld], 1);
    adj16[beg + ticket] = (uint16_t)(u & 0xFFFFu);
  }
}

// ---------- agg1: subgroup(16)=node, 8-edge batches, int8 payload ----------
__global__ __launch_bounds__(256) void agg1_kernel(const int8_t* __restrict__ xq,
    const float* __restrict__ xscale, const uint16_t* __restrict__ adj16,
    const int* __restrict__ rowptr, uint16_t* __restrict__ AGGb, int nNodes) {
  const int sg = threadIdx.x >> 4;
  const int j = threadIdx.x & 15;
  const int n = blockIdx.x * 16 + sg;
  if (n >= nNodes) return;
  const int beg = rowptr[n], end = rowptr[n + 1];
  const bool act = j < 12;
  const int foff = j * 8;  // byte offset: feats 8j..8j+7
  float a0 = 0.f, a1 = 0.f, a2 = 0.f, a3 = 0.f, a4 = 0.f, a5 = 0.f, a6 = 0.f, a7 = 0.f;

  int e = beg;
  if ((e & 1) && e < end) {
    const int s = adj16[e];
    const float sc = xscale[s];
    uint2 v = act ? *(const uint2*)(xq + (size_t)s * IN_DIM + foff) : make_uint2(0u, 0u);
    a0 += sc * i8f(v.x, 0); a1 += sc * i8f(v.x, 1);
    a2 += sc * i8f(v.x, 2); a3 += sc * i8f(v.x, 3);
    a4 += sc * i8f(v.y, 0); a5 += sc * i8f(v.y, 1);
    a6 += sc * i8f(v.y, 2); a7 += sc * i8f(v.y, 3);
    ++e;
  }
  for (; e + 8 <= end; e += 8) {
    const uint32_t p0 = *(const uint32_t*)(adj16 + e);
    const uint32_t p1 = *(const uint32_t*)(adj16 + e + 2);
    const uint32_t p2 = *(const uint32_t*)(adj16 + e + 4);
    const uint32_t p3 = *(const uint32_t*)(adj16 + e + 6);
    const int s[8] = {(int)(p0 & 0xFFFF), (int)(p0 >> 16), (int)(p1 & 0xFFFF), (int)(p1 >> 16),
                      (int)(p2 & 0xFFFF), (int)(p2 >> 16), (int)(p3 & 0xFFFF), (int)(p3 >> 16)};
    uint2 v[8];
    float sc[8];
#pragma unroll
    for (int u = 0; u < 8; ++u) {
      sc[u] = xscale[s[u]];
      v[u] = act ? *(const uint2*)(xq + (size_t)s[u] * IN_DIM + foff) : make_uint2(0u, 0u);
    }
    __builtin_amdgcn_sched_barrier(0);
#pragma unroll
    for (int u = 0; u < 8; ++u) {
      a0 += sc[u] * i8f(v[u].x, 0); a1 += sc[u] * i8f(v[u].x, 1);
      a2 += sc[u] * i8f(v[u].x, 2); a3 += sc[u] * i8f(v[u].x, 3);
      a4 += sc[u] * i8f(v[u].y, 0); a5 += sc[u] * i8f(v[u].y, 1);
      a6 += sc[u] * i8f(v[u].y, 2); a7 += sc[u] * i8f(v[u].y, 3);
    }
  }
  for (; e < end; ++e) {
    const int s = adj16[e];
    const float sc = xscale[s];
    uint2 v = act ? *(const uint2*)(xq + (size_t)s * IN_DIM + foff) : make_uint2(0u, 0u);
    a0 += sc * i8f(v.x, 0); a1 += sc * i8f(v.x, 1);
    a2 += sc * i8f(v.x, 2); a3 += sc * i8f(v.x, 3);
    a4 += sc * i8f(v.y, 0); a5 += sc * i8f(v.y, 1);
    a6 += sc * i8f(v.y, 2); a7 += sc * i8f(v.y, 3);
  }
  if (act) {
    const int d = end - beg;
    const float inv = 1.0f / (float)(d > 1 ? d : 1);
    uint4 o;
    o.x = (uint32_t)f2bf(a0 * inv) | ((uint32_t)f2bf(a1 * inv) << 16);
    o.y = (uint32_t)f2bf(a2 * inv) | ((uint32_t)f2bf(a3 * inv) << 16);
    o.z = (uint32_t)f2bf(a4 * inv) | ((uint32_t)f2bf(a5 * inv) << 16);
    o.w = (uint32_t)f2bf(a6 * inv) | ((uint32_t)f2bf(a7 * inv) << 16);
    *(uint4*)(AGGb + (size_t)n * IN_DIM + foff) = o;
  }
}

// ---------- final: subgroup(16)=node; lane j covers feats 4j..4j+3 (u32 of T2q) ----------
__global__ __launch_bounds__(256) void final_kernel(const int8_t* __restrict__ T2q,
    const float* __restrict__ tscale, const float* __restrict__ R2,
    const uint16_t* __restrict__ adj16, const int* __restrict__ rowptr,
    float* __restrict__ out, int nNodes) {
  const int sg = threadIdx.x >> 4;
  const int j = threadIdx.x & 15;
  const int n = blockIdx.x * 16 + sg;
  if (n >= nNodes) return;
  const int beg = rowptr[n], end = rowptr[n + 1];
  const int foff = j * 4;
  float a0 = 0.f, a1 = 0.f, a2 = 0.f, a3 = 0.f;

  int e = beg;
  if ((e & 1) && e < end) {
    const int s = adj16[e];
    const float sc = tscale[s];
    const uint32_t v = *(const uint32_t*)(T2q + (size_t)s * 64 + foff);
    a0 += sc * i8f(v, 0); a1 += sc * i8f(v, 1); a2 += sc * i8f(v, 2); a3 += sc * i8f(v, 3);
    ++e;
  }
  for (; e + 8 <= end; e += 8) {
    const uint32_t p0 = *(const uint32_t*)(adj16 + e);
    const uint32_t p1 = *(const uint32_t*)(adj16 + e + 2);
    const uint32_t p2 = *(const uint32_t*)(adj16 + e + 4);
    const uint32_t p3 = *(const uint32_t*)(adj16 + e + 6);
    const int s[8] = {(int)(p0 & 0xFFFF), (int)(p0 >> 16), (int)(p1 & 0xFFFF), (int)(p1 >> 16),
                      (int)(p2 & 0xFFFF), (int)(p2 >> 16), (int)(p3 & 0xFFFF), (int)(p3 >> 16)};
    uint32_t v[8];
    float sc[8];
#pragma unroll
    for (int u = 0; u < 8; ++u) {
      sc[u] = tscale[s[u]];
      v[u] = *(const uint32_t*)(T2q + (size_t)s[u] * 64 + foff);
    }
    __builtin_amdgcn_sched_barrier(0);
#pragma unroll
    for (int u = 0; u < 8; ++u) {
      a0 += sc[u] * i8f(v[u], 0); a1 += sc[u] * i8f(v[u], 1);
      a2 += sc[u] * i8f(v[u], 2); a3 += sc[u] * i8f(v[u], 3);
    }
  }
  for (; e < end; ++e) {
    const int s = adj16[e];
    const float sc = tscale[s];
    const uint32_t v = *(const uint32_t*)(T2q + (size_t)s * 64 + foff);
    a0 += sc * i8f(v, 0); a1 += sc * i8f(v, 1); a2 += sc * i8f(v, 2); a3 += sc * i8f(v, 3);
  }
  const int d = end - beg;
  const float inv = 1.0f / (float)(d > 1 ? d : 1);
  const float4 r = *(const float4*)(R2 + (size_t)n * 64 + foff);
  float4 o;
  o.x = a0 * inv + r.x;
  o.y = a1 * inv + r.y;
  o.z = a2 * inv + r.z;
  o.w = a3 * inv + r.w;
  *(float4*)(out + (size_t)n * 64 + foff) = o;
}

// ---------- fused MFMA GEMM1+GEMM2, B staged in LDS; T2 -> int8 row-scaled ----------
#define SP1 200
#define SP2 136
#define HP 136
__global__ __launch_bounds__(256) void gemm12_kernel(
    const uint16_t* __restrict__ AGGb, const uint16_t* __restrict__ xb,
    const uint16_t* __restrict__ S1t, const uint16_t* __restrict__ S2t,
    const float* __restrict__ b1, const float* __restrict__ b2,
    int8_t* __restrict__ T2q, float* __restrict__ tscale, float* __restrict__ R2, int M) {
  __shared__ uint16_t BS[128 * SP1];
  __shared__ uint16_t Hs[64 * HP];
  const int tid = threadIdx.x;
  const int wv = tid >> 6;
  const int lane = tid & 63;
  const int m16 = lane & 15;
  const int quad = lane >> 4;
  const int rowBase = blockIdx.x * 64 + wv * 16;
  int arow = rowBase + m16;
  if (arow >= M) arow = M - 1;
  const int kq = quad * 8;

#pragma unroll
  for (int i = 0; i < 12; ++i) {
    const int idx8 = tid + i * 256;
    const int col = idx8 / 24;
    const int k8 = (idx8 - col * 24) * 8;
    const bf16x8 v = *(const bf16x8*)(S1t + (size_t)idx8 * 8);
    *(bf16x8*)&BS[col * SP1 + k8] = v;
  }
  bf16x8 a1f[6];
#pragma unroll
  for (int s = 0; s < 3; ++s)
    a1f[s] = *(const bf16x8*)(AGGb + (size_t)arow * IN_DIM + s * 32 + kq);
#pragma unroll
  for (int s = 0; s < 3; ++s)
    a1f[3 + s] = *(const bf16x8*)(xb + (size_t)arow * IN_DIM + s * 32 + kq);
  __syncthreads();

  f32x4 acc1[8];
#pragma unroll
  for (int cf = 0; cf < 8; ++cf) acc1[cf] = (f32x4){0.f, 0.f, 0.f, 0.f};
#pragma unroll
  for (int s = 0; s < 6; ++s) {
#pragma unroll
    for (int cf = 0; cf < 8; ++cf) {
      const bf16x8 b = *(const bf16x8*)&BS[(cf * 16 + m16) * SP1 + s * 32 + kq];
      acc1[cf] = __builtin_amdgcn_mfma_f32_16x16x32_bf16(a1f[s], b, acc1[cf], 0, 0, 0);
    }
  }

#pragma unroll
  for (int cf = 0; cf < 8; ++cf) {
    const int col = cf * 16 + m16;
    const float bias = b1[col];
#pragma unroll
    for (int r = 0; r < 4; ++r) {
      const float v = fmaxf(acc1[cf][r] + bias, 0.f);
      Hs[(wv * 16 + quad * 4 + r) * HP + col] = f2bf(v);
    }
  }
  __syncthreads();

#pragma unroll
  for (int i = 0; i < 8; ++i) {
    const int idx8 = tid + i * 256;
    const int col = idx8 >> 4;
    const int k8 = (idx8 & 15) * 8;
    const bf16x8 v = *(const bf16x8*)(S2t + (size_t)idx8 * 8);
    *(bf16x8*)&BS[col * SP2 + k8] = v;
  }
  __syncthreads();

  f32x4 acc2[8];
#pragma unroll
  for (int cf = 0; cf < 8; ++cf) acc2[cf] = (f32x4){0.f, 0.f, 0.f, 0.f};
#pragma unroll
  for (int s = 0; s < 4; ++s) {
    const bf16x8 a = *(const bf16x8*)&Hs[(wv * 16 + m16) * HP + s * 32 + kq];
#pragma unroll
    for (int cf = 0; cf < 8; ++cf) {
      const bf16x8 b = *(const bf16x8*)&BS[(cf * 16 + m16) * SP2 + s * 32 + kq];
      acc2[cf] = __builtin_amdgcn_mfma_f32_16x16x32_bf16(a, b, acc2[cf], 0, 0, 0);
    }
  }

  // epilogue: cols 0..63 (cf 0..3) -> T2q int8 row-scaled; cols 64..127 -> R2 f32 (+b2)
#pragma unroll
  for (int r = 0; r < 4; ++r) {
    float m = 0.f;
#pragma unroll
    for (int cf = 0; cf < 4; ++cf) m = fmaxf(m, fabsf(acc2[cf][r]));
#pragma unroll
    for (int w = 1; w < 16; w <<= 1) m = fmaxf(m, __shfl_xor(m, w));
    m = fmaxf(m, 1e-8f);
    const float is = 127.f / m;
    const int row = rowBase + quad * 4 + r;
    if (row < M) {
#pragma unroll
      for (int cf = 0; cf < 4; ++cf) {
        const int q = __float2int_rn(acc2[cf][r] * is);
        T2q[(size_t)row * 64 + cf * 16 + m16] = (int8_t)q;
      }
      if (m16 == 0) tscale[row] = m / 127.f;
    }
  }
#pragma unroll
  for (int cf = 4; cf < 8; ++cf) {
    const int col = cf * 16 + m16;
#pragma unroll
    for (int r = 0; r < 4; ++r) {
      const int row = rowBase + quad * 4 + r;
      if (row < M) R2[(size_t)row * 64 + (col - 64)] = acc2[cf][r] + b2[col - 64];
    }
  }
}

extern "C" void kernel_launch(void* const* d_in, const int* in_sizes, int n_in,
                              void* d_out, int out_size, void* d_ws, size_t ws_size,
                              hipStream_t stream) {
  const float* x   = (const float*)d_in[0];
  const int*   ei  = (const int*)d_in[1];
  const float* w1l = (const float*)d_in[2];
  const float* b1  = (const float*)d_in[3];
  const float* w1r = (const float*)d_in[4];
  const float* w2l = (const float*)d_in[5];
  const float* b2  = (const float*)d_in[6];
  const float* w2r = (const float*)d_in[7];
  float* out = (float*)d_out;

  const int N = in_sizes[0] / IN_DIM;   // 50000
  const int E = in_sizes[1] / 2;        // 800000
  const int* src = ei;
  const int* dst = ei + E;
  const int NB = (N + 255) >> 8;        // 196 buckets

  // ---- workspace carve (all regions DISJOINT) ----
  char* p = (char*)d_ws;
  uint16_t* AGGb = (uint16_t*)p; p += alignUp((size_t)N * IN_DIM * sizeof(uint16_t), 256);
  int8_t* T2q = (int8_t*)p;      p += alignUp((size_t)N * 64, 256);
  float* tscale = (float*)p;     p += alignUp((size_t)N * sizeof(float), 256);
  float* R2 = (float*)p;         p += alignUp((size_t)N * 64 * sizeof(float), 256);
  uint16_t* xb = (uint16_t*)p;   p += alignUp((size_t)N * IN_DIM * sizeof(uint16_t), 256);
  int8_t* xq = (int8_t*)p;       p += alignUp((size_t)N * IN_DIM, 256);
  float* xscale = (float*)p;     p += alignUp((size_t)N * sizeof(float), 256);
  uint16_t* S1t = (uint16_t*)p;  p += alignUp(NS1 * sizeof(uint16_t), 256);
  uint16_t* S2t = (uint16_t*)p;  p += alignUp(NS2 * sizeof(uint16_t), 256);
  int* rowptr = (int*)p;         p += alignUp((size_t)(N + 1) * sizeof(int), 256);
  uint16_t* adj16 = (uint16_t*)p; p += alignUp((size_t)E * sizeof(uint16_t), 256);
  uint32_t* bucketBuf = (uint32_t*)p; p += alignUp((size_t)E * sizeof(uint32_t), 256);
  int* bucketPart = (int*)p;     p += alignUp(CNT_BLOCKS * 256 * sizeof(int), 256);
  int* bucketBase = (int*)p;     p += alignUp(257 * sizeof(int), 256);
  int* bucketCursor = (int*)p;   p += alignUp(256 * sizeof(int), 256);
  (void)ws_size; (void)n_in; (void)out_size;

  const int total4 = N * IN_DIM / 4;
  const int quantBase = (int)alignUp((size_t)(NS1 + NS2 + total4), 256);
  const int prepThreads = quantBase + 16 * N;
  const int prepBlocks = (prepThreads + 255) / 256;
  count_prep_kernel<<<CNT_BLOCKS + prepBlocks, 256, 0, stream>>>(
      dst, bucketPart, E, x, w1l, w1r, w2l, w2r, S1t, S2t, xb, total4,
      xq, xscale, N, quantBase);
  bucket_scan_kernel<<<1, 256, 0, stream>>>(bucketPart, bucketBase, bucketCursor, rowptr, NB, N);
  bucket_scatter_kernel<<<(E + SCAT_CHUNK - 1) / SCAT_CHUNK, 256, 0, stream>>>(
      src, dst, bucketCursor, bucketBuf, E);
  bucket_build_kernel<<<NB, 256, 0, stream>>>(bucketBuf, bucketBase, rowptr, adj16, N);

  const int nodeBlocks16 = (N + 15) / 16;
  agg1_kernel<<<nodeBlocks16, 256, 0, stream>>>(xq, xscale, adj16, rowptr, AGGb, N);

  const int gemmBlocks = (N + 63) / 64;
  gemm12_kernel<<<gemmBlocks, 256, 0, stream>>>(AGGb, xb, S1t, S2t, b1, b2,
                                                T2q, tscale, R2, N);

  final_kernel<<<nodeBlocks16, 256, 0, stream>>>(T2q, tscale, R2, adj16, rowptr, out, N);
}